// Round 1
// baseline (141.714 us; speedup 1.0000x reference)
//
#include <hip/hip_runtime.h>

#define B_ 96
#define S_ 128
#define C_ 141
#define D_ 768
#define K_ 1536   // 2*D
#define M_ (B_*S_)   // 12288
#define N_ 1536   // 2*D

typedef unsigned short u16;
typedef __bf16 bf16x8 __attribute__((ext_vector_type(8)));
typedef float f32x4 __attribute__((ext_vector_type(4)));

__device__ __forceinline__ u16 f2bf(float x) {
  unsigned int u = __float_as_uint(x);
  u = u + 0x7fffu + ((u >> 16) & 1u);   // RNE
  return (u16)(u >> 16);
}
__device__ __forceinline__ float bf2f(u16 v) {
  return __uint_as_float(((unsigned int)v) << 16);
}

__device__ __forceinline__ void gload_lds16(const void* g, void* l) {
  __builtin_amdgcn_global_load_lds(
      (const __attribute__((address_space(1))) unsigned int*)g,
      (__attribute__((address_space(3))) unsigned int*)l, 16, 0, 0);
}

// ---- pack concat(h0,h1) -> bf16 A [M_ x K_] row-major ----
__global__ void pack_A_kernel(const float* __restrict__ h0, const float* __restrict__ h1,
                              u16* __restrict__ Ap) {
  int idx = blockIdx.x * 256 + threadIdx.x;   // float4 index, total M_*K_/4
  int m = idx / 384;                          // 384 float4 per row
  int c4 = idx - m * 384;
  const float4* src = (c4 < 192)
      ? ((const float4*)h0) + (size_t)m * 192 + c4
      : ((const float4*)h1) + (size_t)m * 192 + (c4 - 192);
  float4 v = *src;
  ushort4 o;
  o.x = f2bf(v.x); o.y = f2bf(v.y); o.z = f2bf(v.z); o.w = f2bf(v.w);
  ((ushort4*)Ap)[idx] = o;
}

// ---- pack W -> bf16 [N_ x K_] row-major (same layout as input) ----
__global__ void pack_W_kernel(const float* __restrict__ W, u16* __restrict__ Wp) {
  int idx = blockIdx.x * 256 + threadIdx.x;   // float4 index, total N_*K_/4
  float4 v = ((const float4*)W)[idx];
  ushort4 o;
  o.x = f2bf(v.x); o.y = f2bf(v.y); o.z = f2bf(v.z); o.w = f2bf(v.w);
  ((ushort4*)Wp)[idx] = o;
}

// ---- char -> token map; intervals are disjoint so scatter is race-free ----
__global__ void tokmap_kernel(const int* __restrict__ om, int* __restrict__ tokmap) {
  __shared__ int st[C_];
  int b = blockIdx.x;
  int t = threadIdx.x;   // block of 192
  if (t < C_) st[t] = -1;
  __syncthreads();
  if (t < S_) {
    int s = om[(b * S_ + t) * 2 + 0];
    int e = om[(b * S_ + t) * 2 + 1];
    for (int c = s; c < e; ++c) st[c] = t;
  }
  __syncthreads();
  if (t < C_) tokmap[b * C_ + t] = st[t];
}

// ---- GEMM: Y[M_ x N_] (bf16) = A[M_ x K_] * W[N_ x K_]^T + bias ----
// 128x128 tile, BK=32, 4 waves (2x2), 16x16x32 MFMA, global_load_lds width-16.
__global__ void __launch_bounds__(256) gemm_kernel(
    const u16* __restrict__ A, const u16* __restrict__ Wt,
    const float* __restrict__ bias, u16* __restrict__ Y) {
  __shared__ u16 As[128 * 32];
  __shared__ u16 Bs[128 * 32];
  const int t = threadIdx.x;
  const int lane = t & 63;
  const int wid = t >> 6;          // 0..3
  const int wm = wid >> 1;         // wave row 0..1
  const int wn = wid & 1;          // wave col 0..1
  const int lr = lane & 15;        // row/col within 16x16
  const int lk = lane >> 4;        // k-group 0..3
  const int n0 = blockIdx.x * 128;
  const int m0 = blockIdx.y * 128;

  f32x4 acc[4][4];
#pragma unroll
  for (int i = 0; i < 4; ++i)
#pragma unroll
    for (int j = 0; j < 4; ++j) acc[i][j] = (f32x4){0.f, 0.f, 0.f, 0.f};

  // staging: per K-step each tile is 128 rows x 32 bf16 = 512 chunks of 16B;
  // thread t stages chunk t (rows 0..63) and chunk t+256 (rows 64..127).
  const int rowc = t >> 2;          // 0..63
  const int koff = (t & 3) * 8;     // bf16 element offset within 32
  const size_t ga0 = (size_t)(m0 + rowc) * K_ + koff;
  const size_t ga1 = (size_t)(m0 + 64 + rowc) * K_ + koff;
  const size_t gb0 = (size_t)(n0 + rowc) * K_ + koff;
  const size_t gb1 = (size_t)(n0 + 64 + rowc) * K_ + koff;
  const int l0 = wid * 1024;        // LDS byte base, load 0 (wave-uniform)
  const int l1 = 4096 + wid * 1024; // LDS byte base, load 1

  for (int kk = 0; kk < K_; kk += 32) {
    __syncthreads();   // previous iter's LDS reads done before overwrite
    gload_lds16(A + ga0 + kk, (char*)As + l0);
    gload_lds16(A + ga1 + kk, (char*)As + l1);
    gload_lds16(Wt + gb0 + kk, (char*)Bs + l0);
    gload_lds16(Wt + gb1 + kk, (char*)Bs + l1);
    __syncthreads();   // compiler drains vmcnt before barrier

    bf16x8 af[4], bfr[4];
#pragma unroll
    for (int mt = 0; mt < 4; ++mt)
      af[mt] = *(const bf16x8*)(As + (wm * 64 + mt * 16 + lr) * 32 + lk * 8);
#pragma unroll
    for (int nt = 0; nt < 4; ++nt)
      bfr[nt] = *(const bf16x8*)(Bs + (wn * 64 + nt * 16 + lr) * 32 + lk * 8);
#pragma unroll
    for (int mt = 0; mt < 4; ++mt)
#pragma unroll
      for (int nt = 0; nt < 4; ++nt)
        acc[mt][nt] = __builtin_amdgcn_mfma_f32_16x16x32_bf16(
            af[mt], bfr[nt], acc[mt][nt], 0, 0, 0);
  }

  // epilogue: D mapping col = lane&15, row = (lane>>4)*4 + reg (m89-verified)
#pragma unroll
  for (int mt = 0; mt < 4; ++mt) {
#pragma unroll
    for (int nt = 0; nt < 4; ++nt) {
      int mrow = m0 + wm * 64 + mt * 16 + lk * 4;
      int ncol = n0 + wn * 64 + nt * 16 + lr;
      float bn = bias[ncol];
#pragma unroll
      for (int r = 0; r < 4; ++r)
        Y[(size_t)(mrow + r) * N_ + ncol] = f2bf(acc[mt][nt][r] + bn);
    }
  }
}

// ---- gather: out_start[b,c,:], out_end[b,c,:] from Y row tokmap[b,c] ----
__global__ void gather_kernel(const u16* __restrict__ Y, const int* __restrict__ tokmap,
                              float* __restrict__ out) {
  int bc = blockIdx.x;            // b*C_ + c
  int b = bc / C_;
  int i = threadIdx.x;            // 0..191; i<96 -> start half, else end half
  int tk = tokmap[bc];
  float4 v0 = {0.f, 0.f, 0.f, 0.f}, v1 = v0;
  if (tk >= 0) {
    const ushort4* yr = (const ushort4*)(Y + (size_t)(b * S_ + tk) * N_);
    int off = (i < 96) ? i * 2 : 192 + (i - 96) * 2;   // ushort4 index in row
    ushort4 a = yr[off], c = yr[off + 1];
    v0 = (float4){bf2f(a.x), bf2f(a.y), bf2f(a.z), bf2f(a.w)};
    v1 = (float4){bf2f(c.x), bf2f(c.y), bf2f(c.z), bf2f(c.w)};
  }
  const size_t half4 = (size_t)B_ * C_ * D_ / 4;  // float4s per output tensor
  float4* o4 = (float4*)out;
  size_t base = (size_t)bc * 192;                 // 192 float4 per (b,c) row
  if (i < 96) {
    o4[base + 2 * i] = v0;
    o4[base + 2 * i + 1] = v1;
  } else {
    o4[half4 + base + 2 * (i - 96)] = v0;
    o4[half4 + base + 2 * (i - 96) + 1] = v1;
  }
}

extern "C" void kernel_launch(void* const* d_in, const int* in_sizes, int n_in,
                              void* d_out, int out_size, void* d_ws, size_t ws_size,
                              hipStream_t stream) {
  (void)in_sizes; (void)n_in; (void)out_size; (void)ws_size;
  const float* h0 = (const float*)d_in[0];
  const float* h1 = (const float*)d_in[1];
  const float* W  = (const float*)d_in[2];
  const float* bias = (const float*)d_in[3];
  const int* om = (const int*)d_in[4];

  char* ws = (char*)d_ws;
  u16* Ap = (u16*)(ws);                 // 12288*1536*2 = 37,748,736 B
  u16* Wp = (u16*)(ws + 37748736);      //  1536*1536*2 =  4,718,592 B
  u16* Y  = (u16*)(ws + 42467328);      // 12288*1536*2 = 37,748,736 B
  int* tokmap = (int*)(ws + 80216064);  //    96*141*4 =     54,144 B
  float* out = (float*)d_out;

  pack_A_kernel<<<M_ * K_ / 4 / 256, 256, 0, stream>>>(h0, h1, Ap);
  pack_W_kernel<<<N_ * K_ / 4 / 256, 256, 0, stream>>>(W, Wp);
  tokmap_kernel<<<B_, 192, 0, stream>>>(om, tokmap);
  gemm_kernel<<<dim3(N_ / 128, M_ / 128), 256, 0, stream>>>(Ap, Wp, bias, Y);
  gather_kernel<<<B_ * C_, 192, 0, stream>>>(Y, tokmap, out);
}

// Round 2
// 89.873 us; speedup vs baseline: 1.5768x; 1.5768x over previous
//
#include <hip/hip_runtime.h>

#define B_ 96
#define S_ 128
#define C_ 141
#define D_ 768
#define K_ 1536   // 2*D
#define M_ (B_*S_)   // 12288 (worst case)
#define N_ 1536   // 2*D

typedef unsigned short u16;
typedef __bf16 bf16x8 __attribute__((ext_vector_type(8)));
typedef float f32x4 __attribute__((ext_vector_type(4)));

__device__ __forceinline__ u16 f2bf(float x) {
  unsigned int u = __float_as_uint(x);
  u = u + 0x7fffu + ((u >> 16) & 1u);   // RNE
  return (u16)(u >> 16);
}
__device__ __forceinline__ float bf2f(u16 v) {
  return __uint_as_float(((unsigned int)v) << 16);
}

__device__ __forceinline__ void gload_lds16(const void* g, void* l) {
  __builtin_amdgcn_global_load_lds(
      (const __attribute__((address_space(1))) unsigned int*)g,
      (__attribute__((address_space(3))) unsigned int*)l, 16, 0, 0);
}

// ---- tokmap + per-batch used-token rank (one block per batch, 192 thr) ----
// used(b,t) = clipped start < clipped end  (disjoint intervals => exactly the
// tokens that ever appear in tokmap).
__global__ void tokmap_rank_kernel(const int* __restrict__ om,
                                   int* __restrict__ tokmap,
                                   int* __restrict__ cidx,
                                   int* __restrict__ cnt) {
  __shared__ int st[C_];
  __shared__ int c0;
  const int b = blockIdx.x;
  const int t = threadIdx.x;   // 0..191
  int s = 0, e = 0;
  if (t < S_) {
    s = om[(b * S_ + t) * 2 + 0];
    e = om[(b * S_ + t) * 2 + 1];
  }
  if (t < C_) st[t] = -1;
  __syncthreads();
  if (t < S_) {
    for (int c = s; c < e; ++c) st[c] = t;   // disjoint -> race-free
  }
  __syncthreads();
  if (t < C_) tokmap[b * C_ + t] = st[t];

  bool used = (t < S_) && (s < e);
  unsigned long long mset = __ballot(used);   // per-wave, 64-bit
  int lane = t & 63;
  int r = __popcll(mset & ((1ull << lane) - 1ull));
  int wcnt = __popcll(mset);
  if (t == 0) c0 = wcnt;          // wave0 count
  __syncthreads();
  int rank = r + ((t >> 6) == 1 ? c0 : 0);
  if (t < S_) cidx[b * S_ + t] = used ? rank : -1;
  if (t == 64) cnt[b] = c0 + wcnt;   // wave1 lane0: total used this batch
}

// ---- exclusive scan of 96 batch counts (single tiny block) ----
__global__ void scan_kernel(const int* __restrict__ cnt, int* __restrict__ boff,
                            int* __restrict__ mc) {
  __shared__ int sc[B_];
  int t = threadIdx.x;   // 128
  if (t < B_) sc[t] = cnt[t];
  __syncthreads();
  if (t == 0) {
    int acc = 0;
    for (int i = 0; i < B_; ++i) { int v = sc[i]; sc[i] = acc; acc += v; }
    mc[0] = acc;                    // Mc: total used rows
    mc[1] = (acc + 127) >> 7;       // number of 128-row m-tiles
  }
  __syncthreads();
  if (t < B_) boff[t] = sc[t];
}

// ---- pack used rows of concat(h0,h1) -> compact bf16 A; fix cidx in place ----
__global__ void pack_A_compact_kernel(const float* __restrict__ h0,
                                      const float* __restrict__ h1,
                                      const int* __restrict__ boff,
                                      int* __restrict__ cidx,
                                      u16* __restrict__ Ap) {
  const int tok = blockIdx.x;     // 0..127
  const int b = blockIdx.y;       // 0..95
  const int i = b * S_ + tok;
  int r = cidx[i];
  if (r < 0) return;
  const int dst = boff[b] + r;
  const int t = threadIdx.x;      // 0..191
  if (t == 0) cidx[i] = dst;      // in-place: rank -> compact row index
  // row = 768 f32 from h0 then 768 f32 from h1; thread t copies 8 elems at 8t
  const float4* src = (t < 96)
      ? ((const float4*)(h0 + (size_t)i * D_)) + 2 * t
      : ((const float4*)(h1 + (size_t)i * D_)) + 2 * (t - 96);
  float4 v0 = src[0], v1 = src[1];
  ushort4 o0, o1;
  o0.x = f2bf(v0.x); o0.y = f2bf(v0.y); o0.z = f2bf(v0.z); o0.w = f2bf(v0.w);
  o1.x = f2bf(v1.x); o1.y = f2bf(v1.y); o1.z = f2bf(v1.z); o1.w = f2bf(v1.w);
  ushort4* dp = (ushort4*)(Ap + (size_t)dst * K_ + 8 * t);
  dp[0] = o0; dp[1] = o1;
}

// ---- pack W -> bf16 [N_ x K_] row-major ----
__global__ void pack_W_kernel(const float* __restrict__ W, u16* __restrict__ Wp) {
  int idx = blockIdx.x * 256 + threadIdx.x;
  float4 v = ((const float4*)W)[idx];
  ushort4 o;
  o.x = f2bf(v.x); o.y = f2bf(v.y); o.z = f2bf(v.z); o.w = f2bf(v.w);
  ((ushort4*)Wp)[idx] = o;
}

// ---- GEMM: Y[Mc x N_] (bf16) = A[Mc x K_] * W[N_ x K_]^T + bias ----
__global__ void __launch_bounds__(256) gemm_kernel(
    const u16* __restrict__ A, const u16* __restrict__ Wt,
    const float* __restrict__ bias, const int* __restrict__ mc,
    u16* __restrict__ Y) {
  if ((int)blockIdx.y >= mc[1]) return;   // early-exit beyond used m-tiles
  __shared__ u16 As[128 * 32];
  __shared__ u16 Bs[128 * 32];
  const int t = threadIdx.x;
  const int lane = t & 63;
  const int wid = t >> 6;
  const int wm = wid >> 1;
  const int wn = wid & 1;
  const int lr = lane & 15;
  const int lk = lane >> 4;
  const int n0 = blockIdx.x * 128;
  const int m0 = blockIdx.y * 128;

  f32x4 acc[4][4];
#pragma unroll
  for (int i = 0; i < 4; ++i)
#pragma unroll
    for (int j = 0; j < 4; ++j) acc[i][j] = (f32x4){0.f, 0.f, 0.f, 0.f};

  const int rowc = t >> 2;
  const int koff = (t & 3) * 8;
  const size_t ga0 = (size_t)(m0 + rowc) * K_ + koff;
  const size_t ga1 = (size_t)(m0 + 64 + rowc) * K_ + koff;
  const size_t gb0 = (size_t)(n0 + rowc) * K_ + koff;
  const size_t gb1 = (size_t)(n0 + 64 + rowc) * K_ + koff;
  const int l0 = wid * 1024;
  const int l1 = 4096 + wid * 1024;

  for (int kk = 0; kk < K_; kk += 32) {
    __syncthreads();
    gload_lds16(A + ga0 + kk, (char*)As + l0);
    gload_lds16(A + ga1 + kk, (char*)As + l1);
    gload_lds16(Wt + gb0 + kk, (char*)Bs + l0);
    gload_lds16(Wt + gb1 + kk, (char*)Bs + l1);
    __syncthreads();

    bf16x8 af[4], bfr[4];
#pragma unroll
    for (int mt = 0; mt < 4; ++mt)
      af[mt] = *(const bf16x8*)(As + (wm * 64 + mt * 16 + lr) * 32 + lk * 8);
#pragma unroll
    for (int nt = 0; nt < 4; ++nt)
      bfr[nt] = *(const bf16x8*)(Bs + (wn * 64 + nt * 16 + lr) * 32 + lk * 8);
#pragma unroll
    for (int mt = 0; mt < 4; ++mt)
#pragma unroll
      for (int nt = 0; nt < 4; ++nt)
        acc[mt][nt] = __builtin_amdgcn_mfma_f32_16x16x32_bf16(
            af[mt], bfr[nt], acc[mt][nt], 0, 0, 0);
  }

#pragma unroll
  for (int mt = 0; mt < 4; ++mt) {
#pragma unroll
    for (int nt = 0; nt < 4; ++nt) {
      int mrow = m0 + wm * 64 + mt * 16 + lk * 4;
      int ncol = n0 + wn * 64 + nt * 16 + lr;
      float bn = bias[ncol];
#pragma unroll
      for (int r = 0; r < 4; ++r)
        Y[(size_t)(mrow + r) * N_ + ncol] = f2bf(acc[mt][nt][r] + bn);
    }
  }
}

// ---- gather through cidx: out_start/out_end[b,c,:] from compact Y ----
__global__ void gather_kernel(const u16* __restrict__ Y,
                              const int* __restrict__ tokmap,
                              const int* __restrict__ cidx,
                              float* __restrict__ out) {
  int bc = blockIdx.x;
  int b = bc / C_;
  int i = threadIdx.x;   // 0..191
  int tk = tokmap[bc];
  float4 v0 = {0.f, 0.f, 0.f, 0.f}, v1 = v0;
  if (tk >= 0) {
    int row = cidx[b * S_ + tk];   // tk covers a char => guaranteed used
    const ushort4* yr = (const ushort4*)(Y + (size_t)row * N_);
    int off = (i < 96) ? i * 2 : 192 + (i - 96) * 2;
    ushort4 a = yr[off], c = yr[off + 1];
    v0 = (float4){bf2f(a.x), bf2f(a.y), bf2f(a.z), bf2f(a.w)};
    v1 = (float4){bf2f(c.x), bf2f(c.y), bf2f(c.z), bf2f(c.w)};
  }
  const size_t half4 = (size_t)B_ * C_ * D_ / 4;
  float4* o4 = (float4*)out;
  size_t base = (size_t)bc * 192;
  if (i < 96) {
    o4[base + 2 * i] = v0;
    o4[base + 2 * i + 1] = v1;
  } else {
    o4[half4 + base + 2 * (i - 96)] = v0;
    o4[half4 + base + 2 * (i - 96) + 1] = v1;
  }
}

extern "C" void kernel_launch(void* const* d_in, const int* in_sizes, int n_in,
                              void* d_out, int out_size, void* d_ws, size_t ws_size,
                              hipStream_t stream) {
  (void)in_sizes; (void)n_in; (void)out_size; (void)ws_size;
  const float* h0 = (const float*)d_in[0];
  const float* h1 = (const float*)d_in[1];
  const float* W  = (const float*)d_in[2];
  const float* bias = (const float*)d_in[3];
  const int* om = (const int*)d_in[4];

  char* ws = (char*)d_ws;
  u16* Ap = (u16*)(ws);                   // 37,748,736 B (worst case all used)
  u16* Wp = (u16*)(ws + 37748736);        //  4,718,592 B
  u16* Y  = (u16*)(ws + 42467328);        // 37,748,736 B
  int* tokmap = (int*)(ws + 80216064);    //     54,144 B
  int* cidx   = (int*)(ws + 80270208);    //     49,152 B
  int* cnt    = (int*)(ws + 80319360);    //        384 B
  int* boff   = (int*)(ws + 80319744);    //        384 B
  int* mc     = (int*)(ws + 80320128);    //         16 B
  float* out = (float*)d_out;

  tokmap_rank_kernel<<<B_, 192, 0, stream>>>(om, tokmap, cidx, cnt);
  scan_kernel<<<1, 128, 0, stream>>>(cnt, boff, mc);
  pack_W_kernel<<<N_ * K_ / 4 / 256, 256, 0, stream>>>(W, Wp);
  pack_A_compact_kernel<<<dim3(S_, B_), 192, 0, stream>>>(h0, h1, boff, cidx, Ap);
  gemm_kernel<<<dim3(N_ / 128, M_ / 128), 256, 0, stream>>>(Ap, Wp, bias, mc, Y);
  gather_kernel<<<B_ * C_, 192, 0, stream>>>(Y, tokmap, cidx, out);
}

// Round 3
// 86.270 us; speedup vs baseline: 1.6427x; 1.0418x over previous
//
#include <hip/hip_runtime.h>

#define B_ 96
#define S_ 128
#define C_ 141
#define D_ 768
#define K_ 1536   // 2*D
#define M_ (B_*S_)   // 12288 (worst case)
#define N_ 1536   // 2*D

typedef unsigned short u16;
typedef __bf16 bf16x8 __attribute__((ext_vector_type(8)));
typedef float f32x4 __attribute__((ext_vector_type(4)));

__device__ __forceinline__ u16 f2bf(float x) {
  unsigned int u = __float_as_uint(x);
  u = u + 0x7fffu + ((u >> 16) & 1u);   // RNE
  return (u16)(u >> 16);
}

__device__ __forceinline__ void gload_lds16(const void* g, void* l) {
  __builtin_amdgcn_global_load_lds(
      (const __attribute__((address_space(1))) unsigned int*)g,
      (__attribute__((address_space(3))) unsigned int*)l, 16, 0, 0);
}

// ---- tokmap + per-batch used-token rank (one block per batch, 192 thr) ----
__global__ void tokmap_rank_kernel(const int* __restrict__ om,
                                   int* __restrict__ tokmap,
                                   int* __restrict__ cidx,
                                   int* __restrict__ cnt) {
  __shared__ int st[C_];
  __shared__ int c0;
  const int b = blockIdx.x;
  const int t = threadIdx.x;   // 0..191
  int s = 0, e = 0;
  if (t < S_) {
    s = om[(b * S_ + t) * 2 + 0];
    e = om[(b * S_ + t) * 2 + 1];
  }
  if (t < C_) st[t] = -1;
  __syncthreads();
  if (t < S_) {
    for (int c = s; c < e; ++c) st[c] = t;   // disjoint -> race-free
  }
  __syncthreads();
  if (t < C_) tokmap[b * C_ + t] = st[t];

  bool used = (t < S_) && (s < e);
  unsigned long long mset = __ballot(used);
  int lane = t & 63;
  int r = __popcll(mset & ((1ull << lane) - 1ull));
  int wcnt = __popcll(mset);
  if (t == 0) c0 = wcnt;
  __syncthreads();
  int rank = r + ((t >> 6) == 1 ? c0 : 0);
  if (t < S_) cidx[b * S_ + t] = used ? rank : -1;
  if (t == 64) cnt[b] = c0 + wcnt;
}

// ---- exclusive scan of 96 batch counts ----
__global__ void scan_kernel(const int* __restrict__ cnt, int* __restrict__ boff,
                            int* __restrict__ mc) {
  __shared__ int sc[B_];
  int t = threadIdx.x;   // 128
  if (t < B_) sc[t] = cnt[t];
  __syncthreads();
  if (t == 0) {
    int acc = 0;
    for (int i = 0; i < B_; ++i) { int v = sc[i]; sc[i] = acc; acc += v; }
    mc[0] = acc;                    // Mc: total used rows
    mc[1] = (acc + 127) >> 7;       // number of 128-row m-tiles
  }
  __syncthreads();
  if (t < B_) boff[t] = sc[t];
}

// ---- pack: compact used rows of concat(h0,h1) -> bf16 A; W -> bf16 ----
__global__ void pack_kernel(const float* __restrict__ h0,
                            const float* __restrict__ h1,
                            const float* __restrict__ W,
                            const int* __restrict__ boff,
                            const int* __restrict__ cidx,
                            u16* __restrict__ Ap, u16* __restrict__ Wp,
                            int* __restrict__ rowinfo) {
  const int blk = blockIdx.x;
  const int t = threadIdx.x;      // 0..191
  if (blk < B_ * S_) {
    const int i = blk;            // b*S + tok
    int r = cidx[i];
    if (r < 0) return;
    const int b = i >> 7;
    const int dst = boff[b] + r;
    if (t == 0) rowinfo[dst] = i;
    const float4* src = (t < 96)
        ? ((const float4*)(h0 + (size_t)i * D_)) + 2 * t
        : ((const float4*)(h1 + (size_t)i * D_)) + 2 * (t - 96);
    float4 v0 = src[0], v1 = src[1];
    ushort4 o0, o1;
    o0.x = f2bf(v0.x); o0.y = f2bf(v0.y); o0.z = f2bf(v0.z); o0.w = f2bf(v0.w);
    o1.x = f2bf(v1.x); o1.y = f2bf(v1.y); o1.z = f2bf(v1.z); o1.w = f2bf(v1.w);
    ushort4* dp = (ushort4*)(Ap + (size_t)dst * K_ + 8 * t);
    dp[0] = o0; dp[1] = o1;
  } else {
    int idx = (blk - B_ * S_) * 192 + t;   // f4 index into W (total 589824)
    float4 v = ((const float4*)W)[idx];
    ushort4 o;
    o.x = f2bf(v.x); o.y = f2bf(v.y); o.z = f2bf(v.z); o.w = f2bf(v.w);
    ((ushort4*)Wp)[idx] = o;
  }
}

// ---- zero-fill uncovered (b,c) output rows ----
__global__ void zerofill_kernel(const int* __restrict__ tokmap,
                                float* __restrict__ out) {
  int bc = blockIdx.x;
  if (tokmap[bc] >= 0) return;
  int t = threadIdx.x;   // 192
  float4 z = {0.f, 0.f, 0.f, 0.f};
  float4* o4 = (float4*)out;
  size_t base = (size_t)bc * 192;              // 192 f4 per (b,c) row
  size_t half4 = (size_t)B_ * C_ * 192;
  o4[base + t] = z;
  o4[half4 + base + t] = z;
}

// ---- GEMM + fused scatter epilogue ----
// acc[Mc x N_] = A[Mc x K_] * W[N_ x K_]^T + bias; row -> out[b, s..e, :]
__global__ void __launch_bounds__(256) gemm_kernel(
    const u16* __restrict__ A, const u16* __restrict__ Wt,
    const float* __restrict__ bias, const int* __restrict__ mc,
    const int* __restrict__ rowinfo, const int* __restrict__ om,
    float* __restrict__ out) {
  // runtime-balanced XCD-chunked swizzle: each XCD gets a contiguous chunk
  // of active work items (n fastest within chunk -> A-panel L2 reuse).
  const int id = blockIdx.y * 12 + blockIdx.x;   // 0..1151
  const int active = mc[1] * 12;
  const int cpx = (active + 7) >> 3;
  const int xcd = id & 7, slot = id >> 3;
  if (slot >= cpx) return;
  const int w = xcd * cpx + slot;
  if (w >= active) return;
  const int mtile = w / 12, ntile = w - mtile * 12;
  const int n0 = ntile * 128;
  const int m0 = mtile * 128;

  __shared__ u16 As[128 * 32];
  __shared__ u16 Bs[128 * 32];
  const int t = threadIdx.x;
  const int lane = t & 63;
  const int wid = t >> 6;
  const int wm = wid >> 1;
  const int wn = wid & 1;
  const int lr = lane & 15;
  const int lk = lane >> 4;

  f32x4 acc[4][4];
#pragma unroll
  for (int i = 0; i < 4; ++i)
#pragma unroll
    for (int j = 0; j < 4; ++j) acc[i][j] = (f32x4){0.f, 0.f, 0.f, 0.f};

  const int rowc = t >> 2;
  const int koff = (t & 3) * 8;
  const size_t ga0 = (size_t)(m0 + rowc) * K_ + koff;
  const size_t ga1 = (size_t)(m0 + 64 + rowc) * K_ + koff;
  const size_t gb0 = (size_t)(n0 + rowc) * K_ + koff;
  const size_t gb1 = (size_t)(n0 + 64 + rowc) * K_ + koff;
  const int l0 = wid * 1024;
  const int l1 = 4096 + wid * 1024;

  for (int kk = 0; kk < K_; kk += 32) {
    __syncthreads();
    gload_lds16(A + ga0 + kk, (char*)As + l0);
    gload_lds16(A + ga1 + kk, (char*)As + l1);
    gload_lds16(Wt + gb0 + kk, (char*)Bs + l0);
    gload_lds16(Wt + gb1 + kk, (char*)Bs + l1);
    __syncthreads();

    bf16x8 af[4], bfr[4];
#pragma unroll
    for (int mt = 0; mt < 4; ++mt)
      af[mt] = *(const bf16x8*)(As + (wm * 64 + mt * 16 + lr) * 32 + lk * 8);
#pragma unroll
    for (int nt = 0; nt < 4; ++nt)
      bfr[nt] = *(const bf16x8*)(Bs + (wn * 64 + nt * 16 + lr) * 32 + lk * 8);
#pragma unroll
    for (int mt = 0; mt < 4; ++mt)
#pragma unroll
      for (int nt = 0; nt < 4; ++nt)
        acc[mt][nt] = __builtin_amdgcn_mfma_f32_16x16x32_bf16(
            af[mt], bfr[nt], acc[mt][nt], 0, 0, 0);
  }

  // fused epilogue: C/D map col = lane&15, row = (lane>>4)*4 + reg (m89)
  const int Mc = mc[0];
  const size_t half = (size_t)B_ * C_ * D_;   // f32 offset of end-tensor
  float bn[4];
#pragma unroll
  for (int nt = 0; nt < 4; ++nt) bn[nt] = bias[n0 + wn * 64 + nt * 16 + lr];

#pragma unroll
  for (int mt = 0; mt < 4; ++mt) {
#pragma unroll
    for (int r = 0; r < 4; ++r) {
      int row = m0 + wm * 64 + mt * 16 + lk * 4 + r;
      if (row < Mc) {
        int i = rowinfo[row];
        int bb = i >> 7;               // / S_
        int s = om[2 * i], e = om[2 * i + 1];
#pragma unroll
        for (int nt = 0; nt < 4; ++nt) {
          int ncol = n0 + wn * 64 + nt * 16 + lr;
          float v = acc[mt][nt][r] + bn[nt];
          size_t colo = (ncol < D_) ? (size_t)ncol
                                    : (size_t)(ncol - D_) + half;
          for (int c = s; c < e; ++c)
            out[(size_t)(bb * C_ + c) * D_ + colo] = v;
        }
      }
    }
  }
}

extern "C" void kernel_launch(void* const* d_in, const int* in_sizes, int n_in,
                              void* d_out, int out_size, void* d_ws, size_t ws_size,
                              hipStream_t stream) {
  (void)in_sizes; (void)n_in; (void)out_size; (void)ws_size;
  const float* h0 = (const float*)d_in[0];
  const float* h1 = (const float*)d_in[1];
  const float* W  = (const float*)d_in[2];
  const float* bias = (const float*)d_in[3];
  const int* om = (const int*)d_in[4];

  char* ws = (char*)d_ws;
  u16* Ap = (u16*)(ws);                   // 37,748,736 B (worst case)
  u16* Wp = (u16*)(ws + 37748736);        //  4,718,592 B
  int* rowinfo = (int*)(ws + 42467328);   //     49,152 B
  int* tokmap  = (int*)(ws + 42516480);   //     54,144 B
  int* cidx    = (int*)(ws + 42570624);   //     49,152 B
  int* cnt     = (int*)(ws + 42619776);   //        384 B
  int* boff    = (int*)(ws + 42620160);   //        384 B
  int* mc      = (int*)(ws + 42620544);   //         16 B
  float* out = (float*)d_out;

  tokmap_rank_kernel<<<B_, 192, 0, stream>>>(om, tokmap, cidx, cnt);
  scan_kernel<<<1, 128, 0, stream>>>(cnt, boff, mc);
  pack_kernel<<<B_ * S_ + 3072, 192, 0, stream>>>(h0, h1, W, boff, cidx,
                                                  Ap, Wp, rowinfo);
  zerofill_kernel<<<B_ * C_, 192, 0, stream>>>(tokmap, out);
  gemm_kernel<<<dim3(12, 96), 256, 0, stream>>>(Ap, Wp, bias, mc,
                                                rowinfo, om, out);
}